// Round 3
// baseline (4477.904 us; speedup 1.0000x reference)
//
#include <hip/hip_runtime.h>
#include <hip/hip_bf16.h>
#include <math.h>

#define BATCH 4
#define SEQ   1024
#define DM    256
#define NH    8
#define DHD   32
#define NL    4
#define FF1   1024
#define OUTD  20

// ---------------------------------------------------------------------------
// padding_mask canonicalization: detect int32 vs uint8 upload, write u8[4096]
// ---------------------------------------------------------------------------
__global__ void pad_kernel(const void* __restrict__ praw, unsigned char* __restrict__ pad)
{
    __shared__ int isInt;
    const int tid = threadIdx.x;  // 1024 threads, 1 block
    const unsigned char* pb = (const unsigned char*)praw;
    if (tid == 0) isInt = 1;
    __syncthreads();
    unsigned char any = 0;
    for (int p = tid; p < BATCH * SEQ; p += 1024)
        if ((p & 3) && pb[p]) any = 1;
    if (any) isInt = 0;  // benign same-value race
    __syncthreads();
    const int ii = isInt;
    for (int e = tid; e < BATCH * SEQ; e += 1024) {
        unsigned char v = ii ? (unsigned char)(((const int*)praw)[e] != 0)
                             : (unsigned char)(pb[e] != 0);
        pad[e] = v;
    }
}

// ---------------------------------------------------------------------------
// blocked[b,i,j] = dmask | pad_j   (u8, 1 = blocked)
// ---------------------------------------------------------------------------
__global__ __launch_bounds__(256) void mask_kernel(const float* __restrict__ P,
                                                   const unsigned char* __restrict__ pad,
                                                   unsigned char* __restrict__ mask)
{
    const int bi = blockIdx.x;            // b*SEQ + i
    const int b = bi >> 10, i = bi & 1023;
    const float* Pb = P + (size_t)b * SEQ * 5;
    const float z1 = Pb[i * 5 + 0], r1 = Pb[i * 5 + 1];
    const float p1 = Pb[i * 5 + 2], e1 = Pb[i * 5 + 3];
    const unsigned char pad_i = pad[bi];
    unsigned char* mrow = mask + (size_t)bi * SEQ;
    const float PI_F  = 3.14159265358979323846f;
    const float TPI_F = 6.28318530717958647692f;
    for (int t = 0; t < 4; ++t) {
        const int j = threadIdx.x + t * 256;
        const unsigned char pad_j = pad[b * SEQ + j];
        unsigned char blockedv;
        if (pad_i || pad_j || i == j) {
            blockedv = pad_j;
        } else {
            const float z2 = Pb[j * 5 + 0], r2 = Pb[j * 5 + 1];
            const float p2 = Pb[j * 5 + 2], e2 = Pb[j * 5 + 3];
            const float rdiff = r2 - r1;
            const float z0 = (rdiff != 0.f) ? fabsf(z1 - r1 * (z2 - z1) / rdiff) : 1e6f;
            float pdiff = fabsf(p2 - p1);
            if (pdiff > PI_F) pdiff = TPI_F - pdiff;
            const float ratio = pdiff / (fabsf(rdiff) + 1e-8f);
            const float ang = sqrtf((e2 - e1) * (e2 - e1) + pdiff * pdiff);
            const bool dm = (z0 > 197.4f) && (ratio > 0.001825f) && (ang > 1.797f);
            blockedv = (dm || pad_j) ? 1 : 0;
        }
        mrow[j] = blockedv;
    }
}

// ---------------------------------------------------------------------------
// x[row, d] = b_in[d] + sum_f in[row,f] * w_in[d,f]   (FIN = 3)
// ---------------------------------------------------------------------------
__global__ __launch_bounds__(256) void embed_kernel(const float* __restrict__ in,
                                                    const float* __restrict__ w_in,
                                                    const float* __restrict__ b_in,
                                                    float* __restrict__ x)
{
    const int row = blockIdx.x;        // 0..4095
    const int d = threadIdx.x;         // 0..255
    const float i0 = in[row * 3 + 0], i1 = in[row * 3 + 1], i2 = in[row * 3 + 2];
    const float v = b_in[d] + i0 * w_in[d * 3 + 0] + i1 * w_in[d * 3 + 1] + i2 * w_in[d * 3 + 2];
    x[row * DM + d] = v;
}

// ---------------------------------------------------------------------------
// C[M,N] = A[M,K] * W[N,K]^T + bias[N], optional ReLU.  64x64 tile, BK=16.
// ---------------------------------------------------------------------------
#define BM 64
#define BN 64
#define BKK 16
__global__ __launch_bounds__(256) void gemm_kernel(const float* __restrict__ A,
                                                   const float* __restrict__ W,
                                                   const float* __restrict__ bias,
                                                   float* __restrict__ C,
                                                   int M, int N, int K, int relu)
{
    __shared__ float As[BKK][BM + 1];
    __shared__ float Ws[BKK][BN + 1];
    const int bm = blockIdx.y, bn = blockIdx.x;
    const int tid = threadIdx.x;
    const int tx = tid & 15, ty = tid >> 4;
    const int arow = tid >> 2;             // 0..63
    const int acol4 = (tid & 3) << 2;      // 0,4,8,12
    const float* Ablk = A + (size_t)(bm * BM + arow) * K;
    const float* Wblk = W + (size_t)(bn * BN + arow) * K;
    float acc[4][4] = {};
    for (int k0 = 0; k0 < K; k0 += BKK) {
        const float4 av = *(const float4*)(Ablk + k0 + acol4);
        const float4 wv = *(const float4*)(Wblk + k0 + acol4);
        As[acol4 + 0][arow] = av.x; As[acol4 + 1][arow] = av.y;
        As[acol4 + 2][arow] = av.z; As[acol4 + 3][arow] = av.w;
        Ws[acol4 + 0][arow] = wv.x; Ws[acol4 + 1][arow] = wv.y;
        Ws[acol4 + 2][arow] = wv.z; Ws[acol4 + 3][arow] = wv.w;
        __syncthreads();
        #pragma unroll
        for (int k = 0; k < BKK; ++k) {
            float a[4], w[4];
            #pragma unroll
            for (int i = 0; i < 4; ++i) a[i] = As[k][ty * 4 + i];
            #pragma unroll
            for (int i = 0; i < 4; ++i) w[i] = Ws[k][tx * 4 + i];
            #pragma unroll
            for (int i = 0; i < 4; ++i)
                #pragma unroll
                for (int j = 0; j < 4; ++j) acc[i][j] += a[i] * w[j];
        }
        __syncthreads();
    }
    #pragma unroll
    for (int i = 0; i < 4; ++i) {
        const int row = bm * BM + ty * 4 + i;
        #pragma unroll
        for (int j = 0; j < 4; ++j) {
            const int col = bn * BN + tx * 4 + j;
            float v = acc[i][j] + bias[col];
            if (relu) v = fmaxf(v, 0.f);
            C[(size_t)row * N + col] = v;
        }
    }
}

// ---------------------------------------------------------------------------
// attention: one wave (64 lanes) per (b, h, q) row.  S=1024 keys, 16/lane.
// qkv layout: [B*S, 768], q at col 0, k at 256, v at 512; head h -> +h*32.
// ---------------------------------------------------------------------------
__global__ __launch_bounds__(256) void attn_kernel(const float* __restrict__ qkv,
                                                   const unsigned char* __restrict__ mask,
                                                   float* __restrict__ out)
{
    const int wave = threadIdx.x >> 6;
    const int lane = threadIdx.x & 63;
    const int row = blockIdx.x * 4 + wave;   // 0..32767 = ((b*8+h)*1024+q)
    const int b = row >> 13;
    const int h = (row >> 10) & 7;
    const int q = row & 1023;

    const float* qrow = qkv + ((size_t)(b * SEQ + q)) * 768 + h * DHD;
    float4 qv[8];
    #pragma unroll
    for (int dd = 0; dd < 8; ++dd) qv[dd] = ((const float4*)qrow)[dd];

    const unsigned char* mrow = mask + ((size_t)(b * SEQ) + q) * SEQ;
    const float scale = 0.17677669529663687f;
    float sc[16];
    #pragma unroll 1
    for (int t = 0; t < 16; ++t) {
        const int j = lane + t * 64;
        const float4* k4 = (const float4*)(qkv + ((size_t)(b * SEQ + j)) * 768 + 256 + h * DHD);
        float s = 0.f;
        #pragma unroll
        for (int dd = 0; dd < 8; ++dd) {
            const float4 kv = k4[dd];
            s += qv[dd].x * kv.x + qv[dd].y * kv.y + qv[dd].z * kv.z + qv[dd].w * kv.w;
        }
        s *= scale;
        if (mrow[j]) s = -1e9f;
        sc[t] = s;
    }
    // softmax across the wave's 1024 scores
    float m = sc[0];
    #pragma unroll
    for (int t = 1; t < 16; ++t) m = fmaxf(m, sc[t]);
    #pragma unroll
    for (int o = 32; o; o >>= 1) m = fmaxf(m, __shfl_xor(m, o, 64));
    float sum = 0.f;
    #pragma unroll
    for (int t = 0; t < 16; ++t) { sc[t] = __expf(sc[t] - m); sum += sc[t]; }
    #pragma unroll
    for (int o = 32; o; o >>= 1) sum += __shfl_xor(sum, o, 64);
    const float inv = 1.f / sum;

    float4 acc[8] = {};
    #pragma unroll 1
    for (int t = 0; t < 16; ++t) {
        const int j = lane + t * 64;
        const float4* v4 = (const float4*)(qkv + ((size_t)(b * SEQ + j)) * 768 + 512 + h * DHD);
        const float p = sc[t];
        #pragma unroll
        for (int dd = 0; dd < 8; ++dd) {
            const float4 vv = v4[dd];
            acc[dd].x += p * vv.x; acc[dd].y += p * vv.y;
            acc[dd].z += p * vv.z; acc[dd].w += p * vv.w;
        }
    }
    // reduce each of the 32 dims across 64 lanes; lane d keeps dim d
    float myval = 0.f;
    #pragma unroll
    for (int dd = 0; dd < 8; ++dd) {
        float c[4] = { acc[dd].x, acc[dd].y, acc[dd].z, acc[dd].w };
        #pragma unroll
        for (int ci = 0; ci < 4; ++ci) {
            float v = c[ci];
            #pragma unroll
            for (int o = 32; o; o >>= 1) v += __shfl_xor(v, o, 64);
            if (lane == dd * 4 + ci) myval = v;
        }
    }
    float* orow = out + ((size_t)(b * SEQ + q)) * DM + h * DHD;
    if (lane < DHD) orow[lane] = myval * inv;
}

// ---------------------------------------------------------------------------
// x = LayerNorm(x + t) * g + b   (row = 4096 rows of 256)
// ---------------------------------------------------------------------------
__global__ __launch_bounds__(256) void add_ln_kernel(float* __restrict__ x,
                                                     const float* __restrict__ t,
                                                     const float* __restrict__ g,
                                                     const float* __restrict__ b)
{
    __shared__ float red[256];
    const int row = blockIdx.x, tid = threadIdx.x;
    const size_t idx = (size_t)row * DM + tid;
    const float v = x[idx] + t[idx];
    red[tid] = v;
    __syncthreads();
    for (int s = 128; s; s >>= 1) { if (tid < s) red[tid] += red[tid + s]; __syncthreads(); }
    const float mean = red[0] * (1.f / DM);
    __syncthreads();
    const float d = v - mean;
    red[tid] = d * d;
    __syncthreads();
    for (int s = 128; s; s >>= 1) { if (tid < s) red[tid] += red[tid + s]; __syncthreads(); }
    const float var = red[0] * (1.f / DM);
    const float rs = rsqrtf(var + 1e-5f);
    x[idx] = d * rs * g[tid] + b[tid];
}

// ---------------------------------------------------------------------------
// out[row, o] = x[row,:] . w_dec[o,:] + b_dec[o]
// ---------------------------------------------------------------------------
__global__ __launch_bounds__(256) void dec_kernel(const float* __restrict__ x,
                                                  const float* __restrict__ w,
                                                  const float* __restrict__ bias,
                                                  float* __restrict__ out)
{
    const int idx = blockIdx.x * 256 + threadIdx.x;
    if (idx >= BATCH * SEQ * OUTD) return;
    const int row = idx / OUTD, o = idx % OUTD;
    const float* xr = x + (size_t)row * DM;
    const float* wr = w + o * DM;
    float s = bias[o];
    for (int d = 0; d < DM; ++d) s += xr[d] * wr[d];
    out[idx] = s;
}

// ---------------------------------------------------------------------------
extern "C" void kernel_launch(void* const* d_in, const int* in_sizes, int n_in,
                              void* d_out, int out_size, void* d_ws, size_t ws_size,
                              hipStream_t stream)
{
    (void)in_sizes; (void)n_in; (void)out_size; (void)ws_size;
    const float* in_coord = (const float*)d_in[0];
    const float* in_maskf = (const float*)d_in[1];
    const void*  praw     = d_in[2];
    const float* w_in  = (const float*)d_in[3];
    const float* b_in  = (const float*)d_in[4];
    const float* w_qkv = (const float*)d_in[5];
    const float* b_qkv = (const float*)d_in[6];
    const float* w_o   = (const float*)d_in[7];
    const float* b_o   = (const float*)d_in[8];
    const float* w_ff1 = (const float*)d_in[9];
    const float* b_ff1 = (const float*)d_in[10];
    const float* w_ff2 = (const float*)d_in[11];
    const float* b_ff2 = (const float*)d_in[12];
    const float* ln1_g = (const float*)d_in[13];
    const float* ln1_b = (const float*)d_in[14];
    const float* ln2_g = (const float*)d_in[15];
    const float* ln2_b = (const float*)d_in[16];
    const float* w_dec = (const float*)d_in[17];
    const float* b_dec = (const float*)d_in[18];

    const int ROWS = BATCH * SEQ;  // 4096
    float* x     = (float*)d_ws;                       // 4096*256   =  4 MB
    float* qkvb  = x     + (size_t)ROWS * DM;          // 4096*768   = 12 MB
    float* attno = qkvb  + (size_t)ROWS * 3 * DM;      // 4096*256   =  4 MB
    float* tmp   = attno + (size_t)ROWS * DM;          // 4096*256   =  4 MB
    float* hbuf  = tmp   + (size_t)ROWS * DM;          // 4096*1024  = 16 MB
    unsigned char* maskb = (unsigned char*)(hbuf + (size_t)ROWS * FF1);  // 4 MB
    unsigned char* padb  = maskb + (size_t)BATCH * SEQ * SEQ;            // 4 KB

    hipLaunchKernelGGL(pad_kernel, dim3(1), dim3(1024), 0, stream, praw, padb);
    hipLaunchKernelGGL(mask_kernel, dim3(BATCH * SEQ), dim3(256), 0, stream,
                       in_maskf, padb, maskb);
    hipLaunchKernelGGL(embed_kernel, dim3(ROWS), dim3(256), 0, stream,
                       in_coord, w_in, b_in, x);

    for (int l = 0; l < NL; ++l) {
        const float* wq = w_qkv + (size_t)l * 3 * DM * DM;
        const float* bq = b_qkv + (size_t)l * 3 * DM;
        const float* wo = w_o   + (size_t)l * DM * DM;
        const float* bo = b_o   + (size_t)l * DM;
        const float* w1 = w_ff1 + (size_t)l * FF1 * DM;
        const float* bb1= b_ff1 + (size_t)l * FF1;
        const float* w2 = w_ff2 + (size_t)l * DM * FF1;
        const float* bb2= b_ff2 + (size_t)l * DM;

        hipLaunchKernelGGL(gemm_kernel, dim3(3 * DM / BN, ROWS / BM), dim3(256), 0, stream,
                           x, wq, bq, qkvb, ROWS, 3 * DM, DM, 0);
        hipLaunchKernelGGL(attn_kernel, dim3(BATCH * NH * SEQ / 4), dim3(256), 0, stream,
                           qkvb, maskb, attno);
        hipLaunchKernelGGL(gemm_kernel, dim3(DM / BN, ROWS / BM), dim3(256), 0, stream,
                           attno, wo, bo, tmp, ROWS, DM, DM, 0);
        hipLaunchKernelGGL(add_ln_kernel, dim3(ROWS), dim3(256), 0, stream,
                           x, tmp, ln1_g + l * DM, ln1_b + l * DM);
        hipLaunchKernelGGL(gemm_kernel, dim3(FF1 / BN, ROWS / BM), dim3(256), 0, stream,
                           x, w1, bb1, hbuf, ROWS, FF1, DM, 1);
        hipLaunchKernelGGL(gemm_kernel, dim3(DM / BN, ROWS / BM), dim3(256), 0, stream,
                           hbuf, w2, bb2, tmp, ROWS, DM, FF1, 0);
        hipLaunchKernelGGL(add_ln_kernel, dim3(ROWS), dim3(256), 0, stream,
                           x, tmp, ln2_g + l * DM, ln2_b + l * DM);
    }

    hipLaunchKernelGGL(dec_kernel, dim3((ROWS * OUTD + 255) / 256), dim3(256), 0, stream,
                       x, w_dec, b_dec, (float*)d_out);
}

// Round 4
// 1729.933 us; speedup vs baseline: 2.5885x; 2.5885x over previous
//
#include <hip/hip_runtime.h>
#include <hip/hip_bf16.h>
#include <math.h>

#define BATCH 4
#define SEQ   1024
#define DM    256
#define NH    8
#define DHD   32
#define NL    4
#define FF1   1024
#define OUTD  20

// ---------------------------------------------------------------------------
// padding_mask canonicalization: detect int32 vs uint8 upload, write u8[4096]
// ---------------------------------------------------------------------------
__global__ void pad_kernel(const void* __restrict__ praw, unsigned char* __restrict__ pad)
{
    __shared__ int isInt;
    const int tid = threadIdx.x;  // 1024 threads, 1 block
    const unsigned char* pb = (const unsigned char*)praw;
    if (tid == 0) isInt = 1;
    __syncthreads();
    unsigned char any = 0;
    for (int p = tid; p < BATCH * SEQ; p += 1024)
        if ((p & 3) && pb[p]) any = 1;
    if (any) isInt = 0;  // benign same-value race
    __syncthreads();
    const int ii = isInt;
    for (int e = tid; e < BATCH * SEQ; e += 1024) {
        unsigned char v = ii ? (unsigned char)(((const int*)praw)[e] != 0)
                             : (unsigned char)(pb[e] != 0);
        pad[e] = v;
    }
}

// ---------------------------------------------------------------------------
// bit-packed blocked mask: mbits[b][i][w] bit j%32 of word j/32 = blocked(i,j)
// ---------------------------------------------------------------------------
__global__ __launch_bounds__(256) void mask_kernel(const float* __restrict__ P,
                                                   const unsigned char* __restrict__ pad,
                                                   unsigned int* __restrict__ mbits)
{
    const int bi = blockIdx.x;            // b*SEQ + i
    const int b = bi >> 10, i = bi & 1023;
    const float* Pb = P + (size_t)b * SEQ * 5;
    const float z1 = Pb[i * 5 + 0], r1 = Pb[i * 5 + 1];
    const float p1 = Pb[i * 5 + 2], e1 = Pb[i * 5 + 3];
    const unsigned char pad_i = pad[bi];
    unsigned int* mrow = mbits + (size_t)bi * (SEQ / 32);
    const float PI_F  = 3.14159265358979323846f;
    const float TPI_F = 6.28318530717958647692f;
    const int lane = threadIdx.x & 63;
    const int wv = threadIdx.x >> 6;
    for (int t = 0; t < 4; ++t) {
        const int j = threadIdx.x + t * 256;
        const unsigned char pad_j = pad[b * SEQ + j];
        bool blocked;
        if (pad_i || pad_j || i == j) {
            blocked = (pad_j != 0);
        } else {
            const float z2 = Pb[j * 5 + 0], r2 = Pb[j * 5 + 1];
            const float p2 = Pb[j * 5 + 2], e2 = Pb[j * 5 + 3];
            const float rdiff = r2 - r1;
            const float z0 = (rdiff != 0.f) ? fabsf(z1 - r1 * (z2 - z1) / rdiff) : 1e6f;
            float pdiff = fabsf(p2 - p1);
            if (pdiff > PI_F) pdiff = TPI_F - pdiff;
            const float ratio = pdiff / (fabsf(rdiff) + 1e-8f);
            const float ang = sqrtf((e2 - e1) * (e2 - e1) + pdiff * pdiff);
            blocked = (z0 > 197.4f) && (ratio > 0.001825f) && (ang > 1.797f);
        }
        const unsigned long long bal = __ballot(blocked);
        if (lane == 0) {
            const int w0 = wv * 2 + t * 8;   // word index = (wv*64 + t*256)/32
            mrow[w0 + 0] = (unsigned int)bal;
            mrow[w0 + 1] = (unsigned int)(bal >> 32);
        }
    }
}

// ---------------------------------------------------------------------------
// x[row, d] = b_in[d] + sum_f in[row,f] * w_in[d,f]   (FIN = 3)
// ---------------------------------------------------------------------------
__global__ __launch_bounds__(256) void embed_kernel(const float* __restrict__ in,
                                                    const float* __restrict__ w_in,
                                                    const float* __restrict__ b_in,
                                                    float* __restrict__ x)
{
    const int row = blockIdx.x;        // 0..4095
    const int d = threadIdx.x;         // 0..255
    const float i0 = in[row * 3 + 0], i1 = in[row * 3 + 1], i2 = in[row * 3 + 2];
    const float v = b_in[d] + i0 * w_in[d * 3 + 0] + i1 * w_in[d * 3 + 1] + i2 * w_in[d * 3 + 2];
    x[row * DM + d] = v;
}

// ---------------------------------------------------------------------------
// C[M,N] = A[M,K] * W[N,K]^T + bias[N], optional ReLU.  64x64 tile, BK=16.
// ---------------------------------------------------------------------------
#define BM 64
#define BN 64
#define BKK 16
__global__ __launch_bounds__(256) void gemm_kernel(const float* __restrict__ A,
                                                   const float* __restrict__ W,
                                                   const float* __restrict__ bias,
                                                   float* __restrict__ C,
                                                   int M, int N, int K, int relu)
{
    __shared__ float As[BKK][BM + 1];
    __shared__ float Ws[BKK][BN + 1];
    const int bm = blockIdx.y, bn = blockIdx.x;
    const int tid = threadIdx.x;
    const int tx = tid & 15, ty = tid >> 4;
    const int arow = tid >> 2;             // 0..63
    const int acol4 = (tid & 3) << 2;      // 0,4,8,12
    const float* Ablk = A + (size_t)(bm * BM + arow) * K;
    const float* Wblk = W + (size_t)(bn * BN + arow) * K;
    float acc[4][4] = {};
    for (int k0 = 0; k0 < K; k0 += BKK) {
        const float4 av = *(const float4*)(Ablk + k0 + acol4);
        const float4 wv = *(const float4*)(Wblk + k0 + acol4);
        As[acol4 + 0][arow] = av.x; As[acol4 + 1][arow] = av.y;
        As[acol4 + 2][arow] = av.z; As[acol4 + 3][arow] = av.w;
        Ws[acol4 + 0][arow] = wv.x; Ws[acol4 + 1][arow] = wv.y;
        Ws[acol4 + 2][arow] = wv.z; Ws[acol4 + 3][arow] = wv.w;
        __syncthreads();
        #pragma unroll
        for (int k = 0; k < BKK; ++k) {
            float a[4], w[4];
            #pragma unroll
            for (int i = 0; i < 4; ++i) a[i] = As[k][ty * 4 + i];
            #pragma unroll
            for (int i = 0; i < 4; ++i) w[i] = Ws[k][tx * 4 + i];
            #pragma unroll
            for (int i = 0; i < 4; ++i)
                #pragma unroll
                for (int j = 0; j < 4; ++j) acc[i][j] += a[i] * w[j];
        }
        __syncthreads();
    }
    #pragma unroll
    for (int i = 0; i < 4; ++i) {
        const int row = bm * BM + ty * 4 + i;
        #pragma unroll
        for (int j = 0; j < 4; ++j) {
            const int col = bn * BN + tx * 4 + j;
            float v = acc[i][j] + bias[col];
            if (relu) v = fmaxf(v, 0.f);
            C[(size_t)row * N + col] = v;
        }
    }
}

// ---------------------------------------------------------------------------
// split heads: qkv[B*S][768] -> Qh/Kh/Vh[(b*8+h)][s][32]
// ---------------------------------------------------------------------------
__global__ __launch_bounds__(256) void split_heads_kernel(const float* __restrict__ qkv,
                                                          float* __restrict__ Qh,
                                                          float* __restrict__ Kh,
                                                          float* __restrict__ Vh)
{
    const int row = blockIdx.x;           // b*1024+s
    const int b = row >> 10, s = row & 1023;
    const int c = threadIdx.x;            // 0..255
    const int h = c >> 5, d = c & 31;
    const size_t dst = (((size_t)(b * NH + h) * SEQ) + s) * DHD + d;
    const float* src = qkv + (size_t)row * 768;
    Qh[dst] = src[c];
    Kh[dst] = src[256 + c];
    Vh[dst] = src[512 + c];
}

// ---------------------------------------------------------------------------
// attention v2: block = 4 waves, each wave 16 queries; lane = (qi, dq):
//   qi = lane>>2 (query within wave), dq = lane&3 (owns dims dq*8..dq*8+7).
// Q and O-accumulator register-stationary; K/V tiles (64x32) staged in LDS
// (stride 36: conflict-free + 16B-aligned); scores reduced over 4 lanes.
// Online softmax per-lane scalar (redundant across the 4 dq lanes).
// ---------------------------------------------------------------------------
#define QBLK  64
#define KTILE 64
__global__ __launch_bounds__(256) void attn2_kernel(const float* __restrict__ Qh,
                                                    const float* __restrict__ Kh,
                                                    const float* __restrict__ Vh,
                                                    const unsigned int* __restrict__ mbits,
                                                    float* __restrict__ out)
{
    __shared__ float Ks[KTILE][36];
    __shared__ float Vs[KTILE][36];
    const int bh = blockIdx.y;          // 0..31
    const int b  = bh >> 3;
    const int h  = bh & 7;
    const int qt = blockIdx.x;          // 0..15
    const int tid = threadIdx.x;
    const int wv = tid >> 6;
    const int lane = tid & 63;
    const int qi = lane >> 2;           // 0..15
    const int dq = lane & 3;            // dims dq*8 .. dq*8+7
    const int q  = qt * QBLK + wv * 16 + qi;

    const float* Qrow = Qh + ((size_t)bh * SEQ + q) * DHD + dq * 8;
    const float4 q0 = *(const float4*)Qrow;
    const float4 q1 = *(const float4*)(Qrow + 4);

    const unsigned int* mrow = mbits + ((size_t)(b * SEQ) + q) * (SEQ / 32);
    const float scale = 0.17677669529663687f;

    float m = -1e30f, l = 0.f;
    float O[8] = {0.f, 0.f, 0.f, 0.f, 0.f, 0.f, 0.f, 0.f};

    for (int t = 0; t < SEQ / KTILE; ++t) {
        __syncthreads();   // previous tile's LDS reads complete
        {
            const float* Ksrc = Kh + ((size_t)bh * SEQ + t * KTILE) * DHD;
            const float* Vsrc = Vh + ((size_t)bh * SEQ + t * KTILE) * DHD;
            #pragma unroll
            for (int u = 0; u < 2; ++u) {
                const int idx = tid + u * 256;       // float4 index 0..511
                const int r = idx >> 3;
                const int c = (idx & 7) << 2;
                *(float4*)(&Ks[r][c]) = *(const float4*)(Ksrc + idx * 4);
                *(float4*)(&Vs[r][c]) = *(const float4*)(Vsrc + idx * 4);
            }
        }
        __syncthreads();

        const unsigned int w0 = mrow[t * 2 + 0];
        const unsigned int w1 = mrow[t * 2 + 1];
        const unsigned long long mb = ((unsigned long long)w1 << 32) | (unsigned long long)w0;

        // phase A: 64 scores (this lane's partial dot over 8 dims, quad-reduced)
        float s[KTILE];
        #pragma unroll
        for (int j = 0; j < KTILE; ++j) {
            const float4 k0 = *(const float4*)(&Ks[j][dq * 8]);
            const float4 k1 = *(const float4*)(&Ks[j][dq * 8 + 4]);
            float acc = q0.x * k0.x + q0.y * k0.y + q0.z * k0.z + q0.w * k0.w
                      + q1.x * k1.x + q1.y * k1.y + q1.z * k1.z + q1.w * k1.w;
            acc += __shfl_xor(acc, 1, 64);
            acc += __shfl_xor(acc, 2, 64);
            s[j] = ((mb >> j) & 1ULL) ? -1e9f : acc * scale;
        }

        // online softmax update (per-lane scalar, redundant over dq)
        float tm = s[0];
        #pragma unroll
        for (int j = 1; j < KTILE; ++j) tm = fmaxf(tm, s[j]);
        const float mnew = fmaxf(m, tm);
        const float resc = __expf(m - mnew);   // 0 on first tile (m = -1e30)
        l *= resc;
        #pragma unroll
        for (int dd = 0; dd < 8; ++dd) O[dd] *= resc;
        m = mnew;

        // phase B: accumulate P·V into register O
        #pragma unroll
        for (int j = 0; j < KTILE; ++j) {
            const float p = __expf(s[j] - m);
            l += p;
            const float4 v0 = *(const float4*)(&Vs[j][dq * 8]);
            const float4 v1 = *(const float4*)(&Vs[j][dq * 8 + 4]);
            O[0] += p * v0.x; O[1] += p * v0.y; O[2] += p * v0.z; O[3] += p * v0.w;
            O[4] += p * v1.x; O[5] += p * v1.y; O[6] += p * v1.z; O[7] += p * v1.w;
        }
    }

    const float inv = 1.f / l;
    float* orow = out + ((size_t)(b * SEQ + q)) * DM + h * DHD + dq * 8;
    float4 o0, o1;
    o0.x = O[0] * inv; o0.y = O[1] * inv; o0.z = O[2] * inv; o0.w = O[3] * inv;
    o1.x = O[4] * inv; o1.y = O[5] * inv; o1.z = O[6] * inv; o1.w = O[7] * inv;
    *(float4*)orow = o0;
    *(float4*)(orow + 4) = o1;
}

// ---------------------------------------------------------------------------
// x = LayerNorm(x + t) * g + b   (row = 4096 rows of 256)
// ---------------------------------------------------------------------------
__global__ __launch_bounds__(256) void add_ln_kernel(float* __restrict__ x,
                                                     const float* __restrict__ t,
                                                     const float* __restrict__ g,
                                                     const float* __restrict__ b)
{
    __shared__ float red[256];
    const int row = blockIdx.x, tid = threadIdx.x;
    const size_t idx = (size_t)row * DM + tid;
    const float v = x[idx] + t[idx];
    red[tid] = v;
    __syncthreads();
    for (int s = 128; s; s >>= 1) { if (tid < s) red[tid] += red[tid + s]; __syncthreads(); }
    const float mean = red[0] * (1.f / DM);
    __syncthreads();
    const float d = v - mean;
    red[tid] = d * d;
    __syncthreads();
    for (int s = 128; s; s >>= 1) { if (tid < s) red[tid] += red[tid + s]; __syncthreads(); }
    const float var = red[0] * (1.f / DM);
    const float rs = rsqrtf(var + 1e-5f);
    x[idx] = d * rs * g[tid] + b[tid];
}

// ---------------------------------------------------------------------------
// out[row, o] = x[row,:] . w_dec[o,:] + b_dec[o]
// ---------------------------------------------------------------------------
__global__ __launch_bounds__(256) void dec_kernel(const float* __restrict__ x,
                                                  const float* __restrict__ w,
                                                  const float* __restrict__ bias,
                                                  float* __restrict__ out)
{
    const int idx = blockIdx.x * 256 + threadIdx.x;
    if (idx >= BATCH * SEQ * OUTD) return;
    const int row = idx / OUTD, o = idx % OUTD;
    const float* xr = x + (size_t)row * DM;
    const float* wr = w + o * DM;
    float s = bias[o];
    for (int d = 0; d < DM; ++d) s += xr[d] * wr[d];
    out[idx] = s;
}

// ---------------------------------------------------------------------------
extern "C" void kernel_launch(void* const* d_in, const int* in_sizes, int n_in,
                              void* d_out, int out_size, void* d_ws, size_t ws_size,
                              hipStream_t stream)
{
    (void)in_sizes; (void)n_in; (void)out_size; (void)ws_size;
    const float* in_coord = (const float*)d_in[0];
    const float* in_maskf = (const float*)d_in[1];
    const void*  praw     = d_in[2];
    const float* w_in  = (const float*)d_in[3];
    const float* b_in  = (const float*)d_in[4];
    const float* w_qkv = (const float*)d_in[5];
    const float* b_qkv = (const float*)d_in[6];
    const float* w_o   = (const float*)d_in[7];
    const float* b_o   = (const float*)d_in[8];
    const float* w_ff1 = (const float*)d_in[9];
    const float* b_ff1 = (const float*)d_in[10];
    const float* w_ff2 = (const float*)d_in[11];
    const float* b_ff2 = (const float*)d_in[12];
    const float* ln1_g = (const float*)d_in[13];
    const float* ln1_b = (const float*)d_in[14];
    const float* ln2_g = (const float*)d_in[15];
    const float* ln2_b = (const float*)d_in[16];
    const float* w_dec = (const float*)d_in[17];
    const float* b_dec = (const float*)d_in[18];

    const int ROWS = BATCH * SEQ;  // 4096
    float* x     = (float*)d_ws;                       // 4096*256   =  4 MB
    float* qkvb  = x     + (size_t)ROWS * DM;          // 4096*768   = 12 MB
    float* attno = qkvb  + (size_t)ROWS * 3 * DM;      // 4096*256   =  4 MB
    float* tmp   = attno + (size_t)ROWS * DM;          // 4096*256   =  4 MB
    float* hbuf  = tmp   + (size_t)ROWS * DM;          // 4096*1024  = 16 MB
    // Qh/Kh/Vh alias hbuf (dead during attention; ff1 overwrites later). 12 MB.
    float* Qh = hbuf;
    float* Kh = hbuf + (size_t)ROWS * DHD * NH;        // +4 MB
    float* Vh = hbuf + 2 * (size_t)ROWS * DHD * NH;    // +8 MB
    unsigned int*  mbits = (unsigned int*)(hbuf + (size_t)ROWS * FF1);   // 512 KB
    unsigned char* padb  = (unsigned char*)(mbits + (size_t)ROWS * (SEQ / 32)); // 4 KB

    hipLaunchKernelGGL(pad_kernel, dim3(1), dim3(1024), 0, stream, praw, padb);
    hipLaunchKernelGGL(mask_kernel, dim3(BATCH * SEQ), dim3(256), 0, stream,
                       in_maskf, padb, mbits);
    hipLaunchKernelGGL(embed_kernel, dim3(ROWS), dim3(256), 0, stream,
                       in_coord, w_in, b_in, x);

    for (int l = 0; l < NL; ++l) {
        const float* wq = w_qkv + (size_t)l * 3 * DM * DM;
        const float* bq = b_qkv + (size_t)l * 3 * DM;
        const float* wo = w_o   + (size_t)l * DM * DM;
        const float* bo = b_o   + (size_t)l * DM;
        const float* w1 = w_ff1 + (size_t)l * FF1 * DM;
        const float* bb1= b_ff1 + (size_t)l * FF1;
        const float* w2 = w_ff2 + (size_t)l * DM * FF1;
        const float* bb2= b_ff2 + (size_t)l * DM;

        hipLaunchKernelGGL(gemm_kernel, dim3(3 * DM / BN, ROWS / BM), dim3(256), 0, stream,
                           x, wq, bq, qkvb, ROWS, 3 * DM, DM, 0);
        hipLaunchKernelGGL(split_heads_kernel, dim3(ROWS), dim3(256), 0, stream,
                           qkvb, Qh, Kh, Vh);
        hipLaunchKernelGGL(attn2_kernel, dim3(SEQ / QBLK, BATCH * NH), dim3(256), 0, stream,
                           Qh, Kh, Vh, mbits, attno);
        hipLaunchKernelGGL(gemm_kernel, dim3(DM / BN, ROWS / BM), dim3(256), 0, stream,
                           attno, wo, bo, tmp, ROWS, DM, DM, 0);
        hipLaunchKernelGGL(add_ln_kernel, dim3(ROWS), dim3(256), 0, stream,
                           x, tmp, ln1_g + l * DM, ln1_b + l * DM);
        hipLaunchKernelGGL(gemm_kernel, dim3(FF1 / BN, ROWS / BM), dim3(256), 0, stream,
                           x, w1, bb1, hbuf, ROWS, FF1, DM, 1);
        hipLaunchKernelGGL(gemm_kernel, dim3(DM / BN, ROWS / BM), dim3(256), 0, stream,
                           hbuf, w2, bb2, tmp, ROWS, DM, FF1, 0);
        hipLaunchKernelGGL(add_ln_kernel, dim3(ROWS), dim3(256), 0, stream,
                           x, tmp, ln2_g + l * DM, ln2_b + l * DM);
    }

    hipLaunchKernelGGL(dec_kernel, dim3((ROWS * OUTD + 255) / 256), dim3(256), 0, stream,
                       x, w_dec, b_dec, (float*)d_out);
}

// Round 12
// 487.093 us; speedup vs baseline: 9.1931x; 3.5515x over previous
//
#include <hip/hip_runtime.h>
#include <math.h>

#define BATCH 4
#define SEQ   1024
#define DM    256
#define NH    8
#define DHD   32
#define NL    4
#define FF1   1024
#define OUTD  20

typedef _Float16 f16;
typedef _Float16 f16x8 __attribute__((ext_vector_type(8)));
typedef _Float16 f16x4 __attribute__((ext_vector_type(4)));
typedef float    f32x4 __attribute__((ext_vector_type(4)));

// ---------------------------------------------------------------------------
// padding_mask canonicalization (int32 vs u8 upload) -> u8[4096]
// ---------------------------------------------------------------------------
__global__ void pad_kernel(const void* __restrict__ praw, unsigned char* __restrict__ pad)
{
    __shared__ int isInt;
    const int tid = threadIdx.x;
    const unsigned char* pb = (const unsigned char*)praw;
    if (tid == 0) isInt = 1;
    __syncthreads();
    unsigned char any = 0;
    for (int p = tid; p < BATCH * SEQ; p += 1024)
        if ((p & 3) && pb[p]) any = 1;
    if (any) isInt = 0;
    __syncthreads();
    const int ii = isInt;
    for (int e = tid; e < BATCH * SEQ; e += 1024)
        pad[e] = ii ? (unsigned char)(((const int*)praw)[e] != 0)
                    : (unsigned char)(pb[e] != 0);
}

// ---------------------------------------------------------------------------
// bit-packed blocked mask
// ---------------------------------------------------------------------------
__global__ __launch_bounds__(256) void mask_kernel(const float* __restrict__ P,
                                                   const unsigned char* __restrict__ pad,
                                                   unsigned int* __restrict__ mbits)
{
    const int bi = blockIdx.x;
    const int b = bi >> 10, i = bi & 1023;
    const float* Pb = P + (size_t)b * SEQ * 5;
    const float z1 = Pb[i * 5 + 0], r1 = Pb[i * 5 + 1];
    const float p1 = Pb[i * 5 + 2], e1 = Pb[i * 5 + 3];
    const unsigned char pad_i = pad[bi];
    unsigned int* mrow = mbits + (size_t)bi * (SEQ / 32);
    const float PI_F  = 3.14159265358979323846f;
    const float TPI_F = 6.28318530717958647692f;
    const int lane = threadIdx.x & 63;
    const int wv = threadIdx.x >> 6;
    for (int t = 0; t < 4; ++t) {
        const int j = threadIdx.x + t * 256;
        const unsigned char pad_j = pad[b * SEQ + j];
        bool blocked;
        if (pad_i || pad_j || i == j) {
            blocked = (pad_j != 0);
        } else {
            const float z2 = Pb[j * 5 + 0], r2 = Pb[j * 5 + 1];
            const float p2 = Pb[j * 5 + 2], e2 = Pb[j * 5 + 3];
            const float rdiff = r2 - r1;
            const float z0 = (rdiff != 0.f) ? fabsf(z1 - r1 * (z2 - z1) / rdiff) : 1e6f;
            float pdiff = fabsf(p2 - p1);
            if (pdiff > PI_F) pdiff = TPI_F - pdiff;
            const float ratio = pdiff / (fabsf(rdiff) + 1e-8f);
            const float ang = sqrtf((e2 - e1) * (e2 - e1) + pdiff * pdiff);
            blocked = (z0 > 197.4f) && (ratio > 0.001825f) && (ang > 1.797f);
        }
        const unsigned long long bal = __ballot(blocked);
        if (lane == 0) {
            const int w0 = wv * 2 + t * 8;
            mrow[w0 + 0] = (unsigned int)bal;
            mrow[w0 + 1] = (unsigned int)(bal >> 32);
        }
    }
}

// ---------------------------------------------------------------------------
// embed: x f32 + xh f16
// ---------------------------------------------------------------------------
__global__ __launch_bounds__(256) void embed_kernel(const float* __restrict__ in,
                                                    const float* __restrict__ w_in,
                                                    const float* __restrict__ b_in,
                                                    float* __restrict__ x,
                                                    f16* __restrict__ xh)
{
    const int row = blockIdx.x;
    const int d = threadIdx.x;
    const float i0 = in[row * 3 + 0], i1 = in[row * 3 + 1], i2 = in[row * 3 + 2];
    const float v = b_in[d] + i0 * w_in[d * 3 + 0] + i1 * w_in[d * 3 + 1] + i2 * w_in[d * 3 + 2];
    x[(size_t)row * DM + d] = v;
    xh[(size_t)row * DM + d] = (f16)v;
}

// ---------------------------------------------------------------------------
// f32 -> f16 weight cast (n multiple of 8)
// ---------------------------------------------------------------------------
__global__ __launch_bounds__(256) void castw_kernel(const float* __restrict__ src,
                                                    f16* __restrict__ dst, int n)
{
    const int i = (blockIdx.x * 256 + threadIdx.x) * 8;
    if (i >= n) return;
    f16x8 o;
    #pragma unroll
    for (int j = 0; j < 8; ++j) o[j] = (f16)src[i + j];
    *(f16x8*)&dst[i] = o;
}

// ---------------------------------------------------------------------------
// MFMA GEMM: C[M,N] = A[M,K](f16) . W[N,K]^T(f16) + bias; relu/of16 flags.
// BT x BT tile, 4 waves (2x2), wave tile BT/2, BK=32, mfma_f32_16x16x32_f16.
// Frag convention: A/B row=lane&15, k=(lane>>4)*8+e;
// D row=(lane>>4)*4+reg (M), col=lane&15 (N).
// ---------------------------------------------------------------------------
template<int BT>
__global__ __launch_bounds__(256) void mgemm_kernel(const f16* __restrict__ A,
                                                    const f16* __restrict__ W,
                                                    const float* __restrict__ bias,
                                                    void* __restrict__ C,
                                                    int M, int N, int K, int relu, int of16)
{
    constexpr int WT = BT / 2;
    constexpr int MF = WT / 16;
    constexpr int LDT = 40;                 // 32 cols + 8 pad
    __shared__ f16 Al[BT * LDT];
    __shared__ f16 Wl[BT * LDT];
    const int tid = threadIdx.x;
    const int lane = tid & 63, g = lane >> 4, fr = lane & 15;
    const int wv = tid >> 6, wm = wv >> 1, wn = wv & 1;
    const int m0 = blockIdx.y * BT, n0 = blockIdx.x * BT;

    f32x4 acc[MF][MF] = {};
    for (int k0 = 0; k0 < K; k0 += 32) {
        __syncthreads();
        #pragma unroll
        for (int u = 0; u < BT / 64; ++u) {
            const int row = (tid >> 2) + u * 64, col = (tid & 3) * 8;
            *(f16x8*)&Al[row * LDT + col] = *(const f16x8*)&A[(size_t)(m0 + row) * K + k0 + col];
            *(f16x8*)&Wl[row * LDT + col] = *(const f16x8*)&W[(size_t)(n0 + row) * K + k0 + col];
        }
        __syncthreads();
        f16x8 af[MF], wf[MF];
        #pragma unroll
        for (int m = 0; m < MF; ++m)
            af[m] = *(const f16x8*)&Al[(wm * WT + m * 16 + fr) * LDT + g * 8];
        #pragma unroll
        for (int n = 0; n < MF; ++n)
            wf[n] = *(const f16x8*)&Wl[(wn * WT + n * 16 + fr) * LDT + g * 8];
        #pragma unroll
        for (int m = 0; m < MF; ++m)
            #pragma unroll
            for (int n = 0; n < MF; ++n)
                acc[m][n] = __builtin_amdgcn_mfma_f32_16x16x32_f16(af[m], wf[n], acc[m][n], 0, 0, 0);
    }
    #pragma unroll
    for (int m = 0; m < MF; ++m)
        #pragma unroll
        for (int n = 0; n < MF; ++n) {
            const int col = n0 + wn * WT + n * 16 + fr;
            const float bs = bias[col];
            #pragma unroll
            for (int r = 0; r < 4; ++r) {
                const int row = m0 + wm * WT + m * 16 + g * 4 + r;
                float v = acc[m][n][r] + bs;
                if (relu) v = fmaxf(v, 0.f);
                if (of16) ((f16*)C)[(size_t)row * N + col] = (f16)v;
                else      ((float*)C)[(size_t)row * N + col] = v;
            }
        }
}

// ---------------------------------------------------------------------------
// split heads (f16): qkv[B*S][768] -> Qh/Kh/Vh[(b*8+h)][s][32]
// ---------------------------------------------------------------------------
__global__ __launch_bounds__(256) void split_heads_kernel(const f16* __restrict__ qkv,
                                                          f16* __restrict__ Qh,
                                                          f16* __restrict__ Kh,
                                                          f16* __restrict__ Vh)
{
    const int row = blockIdx.x;
    const int b = row >> 10, s = row & 1023;
    const int c = threadIdx.x;
    const int h = c >> 5, d = c & 31;
    const size_t dst = (((size_t)(b * NH + h) * SEQ) + s) * DHD + d;
    const f16* src = qkv + (size_t)row * 768;
    Qh[dst] = src[c];
    Kh[dst] = src[256 + c];
    Vh[dst] = src[512 + c];
}

// ---------------------------------------------------------------------------
// MFMA flash attention (f16). Block: 4 waves x 16 queries = 64 q; grid (16,32).
// Swapped QK^T: S^T = mfma(A=K, B=Q) -> lane owns q=lane&15, k=f*16+g*4+r.
// P staged per-wave in LDS with stride 72 (64 keys + 8 pad).
// BUGFIX (R10): Pl stride was 40 (<64 cols) -> rows aliased; now 72.
// ---------------------------------------------------------------------------
__global__ __launch_bounds__(256) void attn3_kernel(const f16* __restrict__ Qh,
                                                    const f16* __restrict__ Kh,
                                                    const f16* __restrict__ Vh,
                                                    const unsigned int* __restrict__ mbits,
                                                    f16* __restrict__ out)
{
    __shared__ f16 Kl[64 * 40];
    __shared__ f16 Vt[32 * 72];      // V^T [d][k], stride 72
    __shared__ f16 Ql[64 * 40];
    __shared__ f16 Pl[4][16 * 72];   // per-wave P: 16 q-rows x 64 keys + pad
    __shared__ unsigned int Ml[64][2];
    const int bh = blockIdx.y, b = bh >> 3, h = bh & 7;
    const int q0 = blockIdx.x * 64;
    const int tid = threadIdx.x, wv = tid >> 6, lane = tid & 63;
    const int g = lane >> 4, fr = lane & 15;
    const size_t kvbase = (size_t)bh * SEQ * DHD;

    {   // stage Q (64x32)
        const int row = tid >> 2, col = (tid & 3) * 8;
        *(f16x8*)&Ql[row * 40 + col] = *(const f16x8*)&Qh[kvbase + (size_t)(q0 + row) * DHD + col];
    }
    const int mrowbase = b * SEQ + q0;
    const float scale = 0.17677669529663687f;
    float mrun = -3.0e38f, lrun = 0.f;
    f32x4 o0 = {0.f, 0.f, 0.f, 0.f}, o1 = {0.f, 0.f, 0.f, 0.f};

    for (int t = 0; t < 16; ++t) {
        __syncthreads();
        {   // stage K tile (64x32)
            const int row = tid >> 2, col = (tid & 3) * 8;
            *(f16x8*)&Kl[row * 40 + col] = *(const f16x8*)&Kh[kvbase + (size_t)(t * 64 + row) * DHD + col];
        }
        {   // stage V^T: thread reads V[k][d0..d0+7], writes transposed
            const int k = tid & 63, d0 = (tid >> 6) * 8;
            const f16x8 v = *(const f16x8*)&Vh[kvbase + (size_t)(t * 64 + k) * DHD + d0];
            #pragma unroll
            for (int j = 0; j < 8; ++j) Vt[(d0 + j) * 72 + k] = v[j];
        }
        if (tid < 128) {   // stage mask words (2 per query)
            const int i = tid >> 1, w = tid & 1;
            Ml[i][w] = mbits[(size_t)(mrowbase + i) * (SEQ / 32) + t * 2 + w];
        }
        __syncthreads();

        const f16x8 bq = *(const f16x8*)&Ql[(wv * 16 + fr) * 40 + g * 8];
        f32x4 s[4];
        #pragma unroll
        for (int f = 0; f < 4; ++f) {
            const f16x8 ak = *(const f16x8*)&Kl[(f * 16 + fr) * 40 + g * 8];
            const f32x4 z = {0.f, 0.f, 0.f, 0.f};
            s[f] = __builtin_amdgcn_mfma_f32_16x16x32_f16(ak, bq, z, 0, 0, 0);
        }
        const unsigned long long mb =
            ((unsigned long long)Ml[wv * 16 + fr][1] << 32) | (unsigned long long)Ml[wv * 16 + fr][0];
        float tm = -3.0e38f;
        #pragma unroll
        for (int f = 0; f < 4; ++f)
            #pragma unroll
            for (int r = 0; r < 4; ++r) {
                const int kk = f * 16 + g * 4 + r;
                const float v = ((mb >> kk) & 1ULL) ? -1e9f : s[f][r] * scale;
                s[f][r] = v;
                tm = fmaxf(tm, v);
            }
        tm = fmaxf(tm, __shfl_xor(tm, 16, 64));
        tm = fmaxf(tm, __shfl_xor(tm, 32, 64));
        const float mnew = fmaxf(mrun, tm);
        const float resc = __expf(mrun - mnew);
        mrun = mnew;
        lrun *= resc;
        float ps = 0.f;
        #pragma unroll
        for (int f = 0; f < 4; ++f)
            #pragma unroll
            for (int r = 0; r < 4; ++r) {
                const float p = __expf(s[f][r] - mnew);
                s[f][r] = p;
                ps += p;
            }
        ps += __shfl_xor(ps, 16, 64);
        ps += __shfl_xor(ps, 32, 64);
        lrun += ps;
        #pragma unroll
        for (int r = 0; r < 4; ++r) {
            const float rs = __shfl(resc, g * 4 + r, 64);
            o0[r] *= rs;
            o1[r] *= rs;
        }
        // P (this lane: q=fr, k=f*16+g*4+0..3) -> f16 -> wave-private LDS
        #pragma unroll
        for (int f = 0; f < 4; ++f) {
            f16x4 pw = { (f16)s[f][0], (f16)s[f][1], (f16)s[f][2], (f16)s[f][3] };
            *(f16x4*)&Pl[wv][fr * 72 + f * 16 + g * 4] = pw;
        }
        #pragma unroll
        for (int kh = 0; kh < 2; ++kh) {
            const f16x8 pa = *(const f16x8*)&Pl[wv][fr * 72 + kh * 32 + g * 8];
            const f16x8 v0 = *(const f16x8*)&Vt[fr * 72 + kh * 32 + g * 8];
            const f16x8 v1 = *(const f16x8*)&Vt[(16 + fr) * 72 + kh * 32 + g * 8];
            o0 = __builtin_amdgcn_mfma_f32_16x16x32_f16(pa, v0, o0, 0, 0, 0);
            o1 = __builtin_amdgcn_mfma_f32_16x16x32_f16(pa, v1, o1, 0, 0, 0);
        }
    }
    #pragma unroll
    for (int r = 0; r < 4; ++r) {
        const float inv = 1.f / __shfl(lrun, g * 4 + r, 64);
        const int qg = q0 + wv * 16 + g * 4 + r;
        f16* orow = out + ((size_t)(b * SEQ + qg)) * DM + h * DHD;
        orow[fr]      = (f16)(o0[r] * inv);
        orow[16 + fr] = (f16)(o1[r] * inv);
    }
}

// ---------------------------------------------------------------------------
// x = LayerNorm(x + t)*g + b ; also f16 mirror xh
// ---------------------------------------------------------------------------
__global__ __launch_bounds__(256) void add_ln_kernel(float* __restrict__ x,
                                                     f16* __restrict__ xh,
                                                     const float* __restrict__ t,
                                                     const float* __restrict__ g,
                                                     const float* __restrict__ b)
{
    __shared__ float red[256];
    const int row = blockIdx.x, tid = threadIdx.x;
    const size_t idx = (size_t)row * DM + tid;
    const float v = x[idx] + t[idx];
    red[tid] = v;
    __syncthreads();
    for (int s = 128; s; s >>= 1) { if (tid < s) red[tid] += red[tid + s]; __syncthreads(); }
    const float mean = red[0] * (1.f / DM);
    __syncthreads();
    const float d = v - mean;
    red[tid] = d * d;
    __syncthreads();
    for (int s = 128; s; s >>= 1) { if (tid < s) red[tid] += red[tid + s]; __syncthreads(); }
    const float var = red[0] * (1.f / DM);
    const float rs = rsqrtf(var + 1e-5f);
    const float o = d * rs * g[tid] + b[tid];
    x[idx] = o;
    xh[idx] = (f16)o;
}

// ---------------------------------------------------------------------------
// decoder (f32)
// ---------------------------------------------------------------------------
__global__ __launch_bounds__(256) void dec_kernel(const float* __restrict__ x,
                                                  const float* __restrict__ w,
                                                  const float* __restrict__ bias,
                                                  float* __restrict__ out)
{
    const int idx = blockIdx.x * 256 + threadIdx.x;
    if (idx >= BATCH * SEQ * OUTD) return;
    const int row = idx / OUTD, o = idx % OUTD;
    const float* xr = x + (size_t)row * DM;
    const float* wr = w + o * DM;
    float s = bias[o];
    for (int d = 0; d < DM; ++d) s += xr[d] * wr[d];
    out[idx] = s;
}

// ---------------------------------------------------------------------------
extern "C" void kernel_launch(void* const* d_in, const int* in_sizes, int n_in,
                              void* d_out, int out_size, void* d_ws, size_t ws_size,
                              hipStream_t stream)
{
    (void)in_sizes; (void)n_in; (void)out_size; (void)ws_size;
    const float* in_coord = (const float*)d_in[0];
    const float* in_maskf = (const float*)d_in[1];
    const void*  praw     = d_in[2];
    const float* w_in  = (const float*)d_in[3];
    const float* b_in  = (const float*)d_in[4];
    const float* w_qkv = (const float*)d_in[5];
    const float* b_qkv = (const float*)d_in[6];
    const float* w_o   = (const float*)d_in[7];
    const float* b_o   = (const float*)d_in[8];
    const float* w_ff1 = (const float*)d_in[9];
    const float* b_ff1 = (const float*)d_in[10];
    const float* w_ff2 = (const float*)d_in[11];
    const float* b_ff2 = (const float*)d_in[12];
    const float* ln1_g = (const float*)d_in[13];
    const float* ln1_b = (const float*)d_in[14];
    const float* ln2_g = (const float*)d_in[15];
    const float* ln2_b = (const float*)d_in[16];
    const float* w_dec = (const float*)d_in[17];
    const float* b_dec = (const float*)d_in[18];

    const int ROWS = BATCH * SEQ;                 // 4096
    float* x   = (float*)d_ws;                    // 1M f32
    float* tmp = x + 1048576;                     // 1M f32
    f16* us = (f16*)(tmp + 1048576);
    f16* xh    = us;  us += 1048576;
    f16* qkvb  = us;  us += 3145728;
    f16* Qh    = us;  us += 1048576;
    f16* Kh    = us;  us += 1048576;
    f16* Vh    = us;  us += 1048576;
    f16* attno = us;  us += 1048576;
    f16* hb    = us;  us += 4194304;
    f16* wqb   = us;  us += 786432;
    f16* wob   = us;  us += 262144;
    f16* w1b   = us;  us += 1048576;
    f16* w2b   = us;  us += 1048576;
    unsigned int*  mbits  = (unsigned int*)us;    // 131072 u32
    unsigned char* padb   = (unsigned char*)(mbits + 131072);

    hipLaunchKernelGGL(pad_kernel, dim3(1), dim3(1024), 0, stream, praw, padb);
    hipLaunchKernelGGL(mask_kernel, dim3(BATCH * SEQ), dim3(256), 0, stream,
                       in_maskf, padb, mbits);
    hipLaunchKernelGGL(embed_kernel, dim3(ROWS), dim3(256), 0, stream,
                       in_coord, w_in, b_in, x, xh);
    hipLaunchKernelGGL(castw_kernel, dim3(786432 / 2048), dim3(256), 0, stream, w_qkv, wqb, 786432);
    hipLaunchKernelGGL(castw_kernel, dim3(262144 / 2048), dim3(256), 0, stream, w_o,  wob, 262144);
    hipLaunchKernelGGL(castw_kernel, dim3(1048576 / 2048), dim3(256), 0, stream, w_ff1, w1b, 1048576);
    hipLaunchKernelGGL(castw_kernel, dim3(1048576 / 2048), dim3(256), 0, stream, w_ff2, w2b, 1048576);

    for (int l = 0; l < NL; ++l) {
        hipLaunchKernelGGL((mgemm_kernel<128>), dim3(768 / 128, ROWS / 128), dim3(256), 0, stream,
                           xh, wqb + (size_t)l * 196608, b_qkv + l * 768, (void*)qkvb,
                           ROWS, 768, 256, 0, 1);
        hipLaunchKernelGGL(split_heads_kernel, dim3(ROWS), dim3(256), 0, stream,
                           qkvb, Qh, Kh, Vh);
        hipLaunchKernelGGL(attn3_kernel, dim3(SEQ / 64, BATCH * NH), dim3(256), 0, stream,
                           Qh, Kh, Vh, mbits, attno);
        hipLaunchKernelGGL((mgemm_kernel<64>), dim3(256 / 64, ROWS / 64), dim3(256), 0, stream,
                           attno, wob + (size_t)l * 65536, b_o + l * 256, (void*)tmp,
                           ROWS, 256, 256, 0, 0);
        hipLaunchKernelGGL(add_ln_kernel, dim3(ROWS), dim3(256), 0, stream,
                           x, xh, tmp, ln1_g + l * DM, ln1_b + l * DM);
        hipLaunchKernelGGL((mgemm_kernel<128>), dim3(1024 / 128, ROWS / 128), dim3(256), 0, stream,
                           xh, w1b + (size_t)l * 262144, b_ff1 + l * 1024, (void*)hb,
                           ROWS, 1024, 256, 1, 1);
        hipLaunchKernelGGL((mgemm_kernel<64>), dim3(256 / 64, ROWS / 64), dim3(256), 0, stream,
                           hb, w2b + (size_t)l * 262144, b_ff2 + l * 256, (void*)tmp,
                           ROWS, 256, 1024, 0, 0);
        hipLaunchKernelGGL(add_ln_kernel, dim3(ROWS), dim3(256), 0, stream,
                           x, xh, tmp, ln2_g + l * DM, ln2_b + l * DM);
    }

    hipLaunchKernelGGL(dec_kernel, dim3((ROWS * OUTD + 255) / 256), dim3(256), 0, stream,
                       x, w_dec, b_dec, (float*)d_out);
}